// Round 1
// baseline (6884.931 us; speedup 1.0000x reference)
//
#include <hip/hip_runtime.h>

#define NN 100000
#define NE 1600000
#define DF 128
#define NC 47
#define NCP 48

constexpr int NPAD = 100352;  // padded node count for ws layout

__global__ __launch_bounds__(256) void deg_kernel(const int* __restrict__ src,
        const int* __restrict__ dst, float* __restrict__ degS, float* __restrict__ degD) {
    int e = blockIdx.x * 256 + threadIdx.x;
    if (e < NE) {
        unsafeAtomicAdd(&degS[src[e]], 1.0f);
        unsafeAtomicAdd(&degD[dst[e]], 1.0f);
    }
}

__global__ __launch_bounds__(256) void norm_kernel(float* __restrict__ degS,
                                                   float* __restrict__ degD) {
    int i = blockIdx.x * 256 + threadIdx.x;
    if (i < NN) {
        degS[i] = rsqrtf(fmaxf(degS[i], 1.0f));
        degD[i] = rsqrtf(fmaxf(degD[i], 1.0f));
    }
}

// Edge-parallel scatter-add: agg[dst] += (RELU? relu(h[src]) : h[src]) * normS[src]
template<int DIN, bool RELU>
__global__ __launch_bounds__(256) void scatter_kernel(const float* __restrict__ h,
        const int* __restrict__ src, const int* __restrict__ dst,
        const float* __restrict__ normS, float* __restrict__ agg) {
    constexpr int TPE = DIN / 4;  // threads per edge, 4 floats each
    int gid = blockIdx.x * 256 + threadIdx.x;
    int e = gid / TPE;
    int c = gid % TPE;
    if (e >= NE) return;
    int s = src[e], d = dst[e];
    float w = normS[s];
    float4 v = *(const float4*)(h + (size_t)s * DIN + c * 4);
    if (RELU) {
        v.x = fmaxf(v.x, 0.f); v.y = fmaxf(v.y, 0.f);
        v.z = fmaxf(v.z, 0.f); v.w = fmaxf(v.w, 0.f);
    }
    float* o = agg + (size_t)d * DIN + c * 4;
    unsafeAtomicAdd(o + 0, v.x * w);
    unsafeAtomicAdd(o + 1, v.y * w);
    unsafeAtomicAdd(o + 2, v.z * w);
    unsafeAtomicAdd(o + 3, v.w * w);
}

// A[N][128] @ W[128][DOUT].  EPI: out = relu?(acc*normD[row] + b[j]), stride DOUT.
// !EPI ("PRE" / GEMM-before-aggregate): out = acc, stride DOUT_PAD, padding cols = 0.
template<int DOUT, int DOUT_PAD, bool EPI, bool ACT>
__global__ __launch_bounds__(256) void gemm_kernel(const float* __restrict__ A,
        const float* __restrict__ W, const float* __restrict__ b,
        const float* __restrict__ normD, float* __restrict__ out) {
    __shared__ float Wl[DF * DOUT_PAD];
    for (int i = threadIdx.x; i < DF * DOUT_PAD; i += 256) {
        int k = i / DOUT_PAD, j = i % DOUT_PAD;
        Wl[i] = (j < DOUT) ? W[k * DOUT + j] : 0.f;
    }
    __syncthreads();
    constexpr int TPR = DOUT_PAD / 4;  // threads per row
    int gid = blockIdx.x * 256 + threadIdx.x;
    int row = gid / TPR;
    int jc = (gid % TPR) * 4;
    if (row >= NN) return;
    const float* arow = A + (size_t)row * DF;
    float accx = 0.f, accy = 0.f, accz = 0.f, accw = 0.f;
    for (int k0 = 0; k0 < DF; k0 += 4) {
        float4 a = *(const float4*)(arow + k0);
        float av;
        float4 w;
        w = *(const float4*)(&Wl[(k0 + 0) * DOUT_PAD + jc]); av = a.x;
        accx += av * w.x; accy += av * w.y; accz += av * w.z; accw += av * w.w;
        w = *(const float4*)(&Wl[(k0 + 1) * DOUT_PAD + jc]); av = a.y;
        accx += av * w.x; accy += av * w.y; accz += av * w.z; accw += av * w.w;
        w = *(const float4*)(&Wl[(k0 + 2) * DOUT_PAD + jc]); av = a.z;
        accx += av * w.x; accy += av * w.y; accz += av * w.z; accw += av * w.w;
        w = *(const float4*)(&Wl[(k0 + 3) * DOUT_PAD + jc]); av = a.w;
        accx += av * w.x; accy += av * w.y; accz += av * w.z; accw += av * w.w;
    }
    if (EPI) {
        float sc = normD[row];
        float o[4] = {accx, accy, accz, accw};
        #pragma unroll
        for (int i = 0; i < 4; i++) {
            int j = jc + i;
            if (j < DOUT) {
                float v = o[i] * sc + b[j];
                if (ACT) v = fmaxf(v, 0.f);
                out[(size_t)row * DOUT + j] = v;
            }
        }
    } else {
        *(float4*)(out + (size_t)row * DOUT_PAD + jc) = make_float4(accx, accy, accz, accw);
    }
}

// Final: out[r][j] = agg[r][j]*normD[r] + b[j]  (no act), agg stride NCP
__global__ __launch_bounds__(256) void epilogue_kernel(const float* __restrict__ agg,
        const float* __restrict__ normD, const float* __restrict__ b,
        float* __restrict__ out) {
    int idx = blockIdx.x * 256 + threadIdx.x;
    if (idx >= NN * NC) return;
    int r = idx / NC, j = idx % NC;
    out[idx] = agg[(size_t)r * NCP + j] * normD[r] + b[j];
}

extern "C" void kernel_launch(void* const* d_in, const int* in_sizes, int n_in,
                              void* d_out, int out_size, void* d_ws, size_t ws_size,
                              hipStream_t stream) {
    const float* x  = (const float*)d_in[0];
    const int*   src = (const int*)d_in[1];
    const int*   dst = (const int*)d_in[2];
    const float* W0 = (const float*)d_in[3];
    const float* b0 = (const float*)d_in[4];
    const float* W1 = (const float*)d_in[5];
    const float* b1 = (const float*)d_in[6];
    const float* W2 = (const float*)d_in[7];
    const float* b2 = (const float*)d_in[8];
    float* out = (float*)d_out;

    float* ws    = (float*)d_ws;
    float* normS = ws;                       // NPAD floats (deg -> norm in place)
    float* normD = ws + NPAD;                // NPAD floats
    float* agg   = ws + 2 * (size_t)NPAD;    // NN*DF floats
    float* h     = agg + (size_t)NN * DF;    // NN*DF floats

    // degrees + norms (ws poisoned each call -> must zero)
    hipMemsetAsync(normS, 0, 2 * (size_t)NPAD * sizeof(float), stream);
    hipMemsetAsync(agg, 0, (size_t)NN * DF * sizeof(float), stream);
    deg_kernel<<<(NE + 255) / 256, 256, 0, stream>>>(src, dst, normS, normD);
    norm_kernel<<<(NN + 255) / 256, 256, 0, stream>>>(normS, normD);

    // layer 0: agg = A^T (relu(x) * normS); h = relu(agg*normD @ W0 + b0)
    scatter_kernel<DF, true><<<NE * (DF / 4) / 256, 256, 0, stream>>>(x, src, dst, normS, agg);
    gemm_kernel<DF, DF, true, true><<<NN * (DF / 4) / 256, 256, 0, stream>>>(agg, W0, b0, normD, h);

    // layer 1 (h already >= 0)
    hipMemsetAsync(agg, 0, (size_t)NN * DF * sizeof(float), stream);
    scatter_kernel<DF, false><<<NE * (DF / 4) / 256, 256, 0, stream>>>(h, src, dst, normS, agg);
    gemm_kernel<DF, DF, true, true><<<NN * (DF / 4) / 256, 256, 0, stream>>>(agg, W1, b1, normD, h);

    // layer 2: GEMM-first (feature-linear ops commute): g = h @ W2 (padded 48) into agg space
    gemm_kernel<NC, NCP, false, false><<<(NN * (NCP / 4) + 255) / 256, 256, 0, stream>>>(
        h, W2, nullptr, nullptr, agg);
    // agg2 (= h space, NN*48 floats) must be zeroed after gemm-first consumed h
    hipMemsetAsync(h, 0, (size_t)NN * NCP * sizeof(float), stream);
    scatter_kernel<NCP, false><<<NE * (NCP / 4) / 256, 256, 0, stream>>>(agg, src, dst, normS, h);
    epilogue_kernel<<<(NN * NC + 255) / 256, 256, 0, stream>>>(h, normD, b2, out);
}

// Round 3
// 1104.702 us; speedup vs baseline: 6.2324x; 6.2324x over previous
//
#include <hip/hip_runtime.h>

#define NN 100000
#define NE 1600000
#define DF 128
#define NC 47
#define NCP 48

constexpr int NPAD = 100352;  // padded node count for ws layout

// Degree counts as ints: cntS (into normS buffer, punned), cntD separate (kept for CSR).
__global__ __launch_bounds__(256) void deg_kernel(const int* __restrict__ src,
        const int* __restrict__ dst, int* __restrict__ cntS, int* __restrict__ cntD) {
    int e = blockIdx.x * 256 + threadIdx.x;
    if (e < NE) {
        atomicAdd(&cntS[src[e]], 1);
        atomicAdd(&cntD[dst[e]], 1);
    }
}

// normS: in-place int count -> rsqrt float. normD: from cntD (cntD preserved).
__global__ __launch_bounds__(256) void norm_kernel(float* __restrict__ normS,
        const int* __restrict__ cntD, float* __restrict__ normD) {
    int i = blockIdx.x * 256 + threadIdx.x;
    if (i < NN) {
        int cs = ((const int*)normS)[i];
        normS[i] = rsqrtf(fmaxf((float)cs, 1.0f));
        normD[i] = rsqrtf(fmaxf((float)cntD[i], 1.0f));
    }
}

// Single-workgroup exclusive scan of cntD[NN] -> rowptr[NN+1]
__global__ __launch_bounds__(1024) void scan_kernel(const int* __restrict__ cnt,
                                                    int* __restrict__ rowptr) {
    __shared__ int part[1024];
    const int t = threadIdx.x;
    const int CH = (NN + 1023) / 1024;  // 98
    const int base = t * CH;
    int s = 0;
    for (int i = 0; i < CH; i++) {
        int idx = base + i;
        if (idx < NN) s += cnt[idx];
    }
    part[t] = s;
    __syncthreads();
    for (int off = 1; off < 1024; off <<= 1) {
        int v = (t >= off) ? part[t - off] : 0;
        __syncthreads();
        part[t] += v;
        __syncthreads();
    }
    int run = (t == 0) ? 0 : part[t - 1];
    for (int i = 0; i < CH; i++) {
        int idx = base + i;
        if (idx < NN) { rowptr[idx] = run; run += cnt[idx]; }
    }
    if (t == 1023) rowptr[NN] = part[1023];
}

// Counting-sort edges by dst: csr[rowptr[d] + fill[d]++] = src
__global__ __launch_bounds__(256) void fill_kernel(const int* __restrict__ src,
        const int* __restrict__ dst, const int* __restrict__ rowptr,
        int* __restrict__ fill, int* __restrict__ csr) {
    int e = blockIdx.x * 256 + threadIdx.x;
    if (e < NE) {
        int d = dst[e];
        int pos = rowptr[d] + atomicAdd(&fill[d], 1);
        csr[pos] = src[e];
    }
}

// xs = relu(x) * normS[row]   (layer-0 input prep)
__global__ __launch_bounds__(256) void prescale_kernel(const float* __restrict__ x,
        const float* __restrict__ normS, float* __restrict__ xs) {
    int idx = blockIdx.x * 256 + threadIdx.x;  // over NN*32 float4s
    int row = idx >> 5;
    if (row >= NN) return;
    float w = normS[row];
    float4 v = ((const float4*)x)[idx];
    v.x = fmaxf(v.x, 0.f) * w; v.y = fmaxf(v.y, 0.f) * w;
    v.z = fmaxf(v.z, 0.f) * w; v.w = fmaxf(v.w, 0.f) * w;
    ((float4*)xs)[idx] = v;
}

// One wave per node: out[node][:] = sum over CSR neighbors of hs[s][:]. 128 wide.
__global__ __launch_bounds__(256) void gather128_kernel(const float* __restrict__ hs,
        const int* __restrict__ rowptr, const int* __restrict__ csr,
        float* __restrict__ out) {
    int node = __builtin_amdgcn_readfirstlane(blockIdx.x * 4 + (threadIdx.x >> 6));
    int lane = threadIdx.x & 63;
    if (node >= NN) return;
    int beg = rowptr[node], end = rowptr[node + 1];
    float2 acc = {0.f, 0.f}, acc2 = {0.f, 0.f};
    int j = beg;
    for (; j + 1 < end; j += 2) {
        int s0 = csr[j], s1 = csr[j + 1];
        float2 v0 = *(const float2*)(hs + (size_t)s0 * DF + lane * 2);
        float2 v1 = *(const float2*)(hs + (size_t)s1 * DF + lane * 2);
        acc.x += v0.x; acc.y += v0.y;
        acc2.x += v1.x; acc2.y += v1.y;
    }
    if (j < end) {
        float2 v = *(const float2*)(hs + (size_t)csr[j] * DF + lane * 2);
        acc.x += v.x; acc.y += v.y;
    }
    acc.x += acc2.x; acc.y += acc2.y;
    *(float2*)(out + (size_t)node * DF + lane * 2) = acc;
}

// One wave per node, 48 wide (lanes 0..47, 1 float each)
__global__ __launch_bounds__(256) void gather48_kernel(const float* __restrict__ g,
        const int* __restrict__ rowptr, const int* __restrict__ csr,
        float* __restrict__ out) {
    int node = __builtin_amdgcn_readfirstlane(blockIdx.x * 4 + (threadIdx.x >> 6));
    int lane = threadIdx.x & 63;
    if (node >= NN) return;
    int beg = rowptr[node], end = rowptr[node + 1];
    float acc = 0.f, acc2 = 0.f;
    int j = beg;
    for (; j + 1 < end; j += 2) {
        int s0 = csr[j], s1 = csr[j + 1];
        if (lane < NCP) {
            acc  += g[(size_t)s0 * NCP + lane];
            acc2 += g[(size_t)s1 * NCP + lane];
        }
    }
    if (j < end && lane < NCP) acc += g[(size_t)csr[j] * NCP + lane];
    if (lane < NCP) out[(size_t)node * NCP + lane] = acc + acc2;
}

// A[N][128] @ W[128][DOUT].
// EPI: out = relu?(acc*normD[row] + b[j]) * (NS ? normS[row] : 1), stride DOUT.
// !EPI: out = acc, stride DOUT_PAD (padding cols produce 0 since Wl padded with 0).
template<int DOUT, int DOUT_PAD, bool EPI, bool ACT, bool NS>
__global__ __launch_bounds__(256) void gemm_kernel(const float* __restrict__ A,
        const float* __restrict__ W, const float* __restrict__ b,
        const float* __restrict__ normD, const float* __restrict__ normS,
        float* __restrict__ out) {
    __shared__ float Wl[DF * DOUT_PAD];
    for (int i = threadIdx.x; i < DF * DOUT_PAD; i += 256) {
        int k = i / DOUT_PAD, j = i % DOUT_PAD;
        Wl[i] = (j < DOUT) ? W[k * DOUT + j] : 0.f;
    }
    __syncthreads();
    constexpr int TPR = DOUT_PAD / 4;  // threads per row
    int gid = blockIdx.x * 256 + threadIdx.x;
    int row = gid / TPR;
    int jc = (gid % TPR) * 4;
    if (row >= NN) return;
    const float* arow = A + (size_t)row * DF;
    float accx = 0.f, accy = 0.f, accz = 0.f, accw = 0.f;
    for (int k0 = 0; k0 < DF; k0 += 4) {
        float4 a = *(const float4*)(arow + k0);
        float av;
        float4 w;
        w = *(const float4*)(&Wl[(k0 + 0) * DOUT_PAD + jc]); av = a.x;
        accx += av * w.x; accy += av * w.y; accz += av * w.z; accw += av * w.w;
        w = *(const float4*)(&Wl[(k0 + 1) * DOUT_PAD + jc]); av = a.y;
        accx += av * w.x; accy += av * w.y; accz += av * w.z; accw += av * w.w;
        w = *(const float4*)(&Wl[(k0 + 2) * DOUT_PAD + jc]); av = a.z;
        accx += av * w.x; accy += av * w.y; accz += av * w.z; accw += av * w.w;
        w = *(const float4*)(&Wl[(k0 + 3) * DOUT_PAD + jc]); av = a.w;
        accx += av * w.x; accy += av * w.y; accz += av * w.z; accw += av * w.w;
    }
    if (EPI) {
        float sd = normD[row];
        float ss = NS ? normS[row] : 1.f;
        float o[4] = {accx, accy, accz, accw};
        #pragma unroll
        for (int i = 0; i < 4; i++) {
            int j = jc + i;
            if (j < DOUT) {
                float v = o[i] * sd + b[j];
                if (ACT) v = fmaxf(v, 0.f);
                out[(size_t)row * DOUT + j] = v * ss;
            }
        }
    } else {
        *(float4*)(out + (size_t)row * DOUT_PAD + jc) = make_float4(accx, accy, accz, accw);
    }
}

// Final: out[r][j] = agg[r][j]*normD[r] + b[j]  (no act), agg stride NCP
__global__ __launch_bounds__(256) void epilogue_kernel(const float* __restrict__ agg,
        const float* __restrict__ normD, const float* __restrict__ b,
        float* __restrict__ out) {
    int idx = blockIdx.x * 256 + threadIdx.x;
    if (idx >= NN * NC) return;
    int r = idx / NC, j = idx % NC;
    out[idx] = agg[(size_t)r * NCP + j] * normD[r] + b[j];
}

extern "C" void kernel_launch(void* const* d_in, const int* in_sizes, int n_in,
                              void* d_out, int out_size, void* d_ws, size_t ws_size,
                              hipStream_t stream) {
    const float* x   = (const float*)d_in[0];
    const int*   src = (const int*)d_in[1];
    const int*   dst = (const int*)d_in[2];
    const float* W0  = (const float*)d_in[3];
    const float* b0  = (const float*)d_in[4];
    const float* W1  = (const float*)d_in[5];
    const float* b1  = (const float*)d_in[6];
    const float* W2  = (const float*)d_in[7];
    const float* b2  = (const float*)d_in[8];
    float* out = (float*)d_out;

    float* ws     = (float*)d_ws;
    float* normS  = ws;                          // NPAD floats (int counts -> float in place)
    float* normD  = ws + NPAD;                   // NPAD floats
    int*   cntD   = (int*)(ws + 2 * (size_t)NPAD);   // NPAD ints (counts, then fill ctr)
    int*   rowptr = cntD + NPAD;                 // NPAD ints (NN+1 used)
    int*   csr    = rowptr + NPAD;               // NE ints
    float* bufA   = (float*)(csr + NE);          // NN*DF floats
    float* bufB   = bufA + (size_t)NN * DF;      // NN*DF floats

    // ---- graph prep (per-launch; ws is poisoned each call) ----
    hipMemsetAsync(normS, 0, NPAD * sizeof(int), stream);
    hipMemsetAsync(cntD, 0, NPAD * sizeof(int), stream);
    deg_kernel<<<(NE + 255) / 256, 256, 0, stream>>>(src, dst, (int*)normS, cntD);
    scan_kernel<<<1, 1024, 0, stream>>>(cntD, rowptr);
    norm_kernel<<<(NN + 255) / 256, 256, 0, stream>>>(normS, cntD, normD);
    hipMemsetAsync(cntD, 0, NPAD * sizeof(int), stream);  // reuse as fill counters
    fill_kernel<<<(NE + 255) / 256, 256, 0, stream>>>(src, dst, rowptr, cntD, csr);

    // ---- layer 0: A = relu(x)*normS; B = gather(A); A = relu(B*normD @ W0 + b0)*normS
    prescale_kernel<<<NN * (DF / 16) / 16, 256, 0, stream>>>(x, normS, bufA);  // NN*32/256
    gather128_kernel<<<(NN + 3) / 4, 256, 0, stream>>>(bufA, rowptr, csr, bufB);
    gemm_kernel<DF, DF, true, true, true><<<NN * (DF / 4) / 256, 256, 0, stream>>>(
        bufB, W0, b0, normD, normS, bufA);

    // ---- layer 1: B = gather(A); A = relu(B*normD @ W1 + b1)*normS
    gather128_kernel<<<(NN + 3) / 4, 256, 0, stream>>>(bufA, rowptr, csr, bufB);
    gemm_kernel<DF, DF, true, true, true><<<NN * (DF / 4) / 256, 256, 0, stream>>>(
        bufB, W1, b1, normD, normS, bufA);

    // ---- layer 2 (GEMM-first): B = A @ W2 (48-wide); A = gather48(B); out = A*normD + b2
    gemm_kernel<NC, NCP, false, false, false><<<(NN * (NCP / 4) + 255) / 256, 256, 0, stream>>>(
        bufA, W2, nullptr, nullptr, nullptr, bufB);
    gather48_kernel<<<(NN + 3) / 4, 256, 0, stream>>>(bufB, rowptr, csr, bufA);
    epilogue_kernel<<<(NN * NC + 255) / 256, 256, 0, stream>>>(bufA, normD, b2, out);
}

// Round 5
// 866.321 us; speedup vs baseline: 7.9473x; 1.2752x over previous
//
#include <hip/hip_runtime.h>

#define NN 100000
#define NE 1600000
#define DF 128
#define NC 47
#define NCP 48

constexpr int NPAD = 100352;   // padded node count (= 98 * 1024)
constexpr int SBLK = 98;       // scan blocks

// Degree counts as ints: cntS (into normS buffer, punned), cntD separate (kept for CSR).
__global__ __launch_bounds__(256) void deg_kernel(const int* __restrict__ src,
        const int* __restrict__ dst, int* __restrict__ cntS, int* __restrict__ cntD) {
    int e = blockIdx.x * 256 + threadIdx.x;
    if (e < NE) {
        atomicAdd(&cntS[src[e]], 1);
        atomicAdd(&cntD[dst[e]], 1);
    }
}

// normS: in-place int count -> rsqrt float. normD: from cntD (cntD preserved).
__global__ __launch_bounds__(256) void norm_kernel(float* __restrict__ normS,
        const int* __restrict__ cntD, float* __restrict__ normD) {
    int i = blockIdx.x * 256 + threadIdx.x;
    if (i < NN) {
        int cs = ((const int*)normS)[i];
        normS[i] = rsqrtf(fmaxf((float)cs, 1.0f));
        normD[i] = rsqrtf(fmaxf((float)cntD[i], 1.0f));
    }
}

// ---- 3-pass exclusive scan of cnt[NPAD] -> rowptr (pass1 local excl + block sums) ----
__global__ __launch_bounds__(1024) void scan1_kernel(const int* __restrict__ cnt,
        int* __restrict__ rowptr, int* __restrict__ bsum) {
    __shared__ int tmp[1024];
    int t = threadIdx.x;
    int g = blockIdx.x * 1024 + t;
    int v = cnt[g];          // g < NPAD always; tail (>= NN) is zeroed
    tmp[t] = v;
    __syncthreads();
    for (int off = 1; off < 1024; off <<= 1) {
        int u = (t >= off) ? tmp[t - off] : 0;
        __syncthreads();
        tmp[t] += u;
        __syncthreads();
    }
    rowptr[g] = tmp[t] - v;                    // exclusive within block
    if (t == 1023) bsum[blockIdx.x] = tmp[t];  // block total
}

__global__ __launch_bounds__(128) void scan2_kernel(int* __restrict__ bsum) {
    __shared__ int tmp[128];
    int t = threadIdx.x;
    int v = (t < SBLK) ? bsum[t] : 0;
    tmp[t] = v;
    __syncthreads();
    for (int off = 1; off < 128; off <<= 1) {
        int u = (t >= off) ? tmp[t - off] : 0;
        __syncthreads();
        tmp[t] += u;
        __syncthreads();
    }
    if (t < SBLK) bsum[t] = tmp[t] - v;        // exclusive block offsets, in place
}

__global__ __launch_bounds__(1024) void scan3_kernel(int* __restrict__ rowptr,
        const int* __restrict__ bsum) {
    int g = blockIdx.x * 1024 + threadIdx.x;   // g < NPAD
    rowptr[g] += bsum[blockIdx.x];
}

// Counting-sort edges by dst: csr[rowptr[d] + fill[d]++] = src
__global__ __launch_bounds__(256) void fill_kernel(const int* __restrict__ src,
        const int* __restrict__ dst, const int* __restrict__ rowptr,
        int* __restrict__ fill, int* __restrict__ csr) {
    int e = blockIdx.x * 256 + threadIdx.x;
    if (e < NE) {
        int d = dst[e];
        int pos = rowptr[d] + atomicAdd(&fill[d], 1);
        csr[pos] = src[e];
    }
}

// One wave per node: out[node][:] = sum over CSR neighbors of f(hs[s][:]). 128 wide.
// PRE: f = relu(.) * normS[s]  (layer-0, reads x directly). Else f = identity.
template<bool PRE>
__global__ __launch_bounds__(256) void gather128_kernel(const float* __restrict__ hs,
        const float* __restrict__ normS, const int* __restrict__ rowptr,
        const int* __restrict__ csr, float* __restrict__ out) {
    int node = __builtin_amdgcn_readfirstlane(blockIdx.x * 4 + (threadIdx.x >> 6));
    int lane = threadIdx.x & 63;
    if (node >= NN) return;
    int beg = rowptr[node], end = rowptr[node + 1];
    float2 acc = {0.f, 0.f}, acc2 = {0.f, 0.f};
    int j = beg;
    for (; j + 1 < end; j += 2) {
        int s0 = csr[j], s1 = csr[j + 1];
        float2 v0 = *(const float2*)(hs + (size_t)s0 * DF + lane * 2);
        float2 v1 = *(const float2*)(hs + (size_t)s1 * DF + lane * 2);
        if (PRE) {
            float w0 = normS[s0], w1 = normS[s1];
            v0.x = fmaxf(v0.x, 0.f) * w0; v0.y = fmaxf(v0.y, 0.f) * w0;
            v1.x = fmaxf(v1.x, 0.f) * w1; v1.y = fmaxf(v1.y, 0.f) * w1;
        }
        acc.x += v0.x; acc.y += v0.y;
        acc2.x += v1.x; acc2.y += v1.y;
    }
    if (j < end) {
        int s = csr[j];
        float2 v = *(const float2*)(hs + (size_t)s * DF + lane * 2);
        if (PRE) {
            float w = normS[s];
            v.x = fmaxf(v.x, 0.f) * w; v.y = fmaxf(v.y, 0.f) * w;
        }
        acc.x += v.x; acc.y += v.y;
    }
    acc.x += acc2.x; acc.y += acc2.y;
    *(float2*)(out + (size_t)node * DF + lane * 2) = acc;
}

// One wave per node, 48 wide; fused final epilogue: out[n][j] = acc*normD[n] + b2[j]
__global__ __launch_bounds__(256) void gather48_kernel(const float* __restrict__ g,
        const int* __restrict__ rowptr, const int* __restrict__ csr,
        const float* __restrict__ normD, const float* __restrict__ b2,
        float* __restrict__ out) {
    int node = __builtin_amdgcn_readfirstlane(blockIdx.x * 4 + (threadIdx.x >> 6));
    int lane = threadIdx.x & 63;
    if (node >= NN) return;
    int beg = rowptr[node], end = rowptr[node + 1];
    float acc = 0.f, acc2 = 0.f;
    int j = beg;
    for (; j + 1 < end; j += 2) {
        int s0 = csr[j], s1 = csr[j + 1];
        if (lane < NCP) {
            acc  += g[(size_t)s0 * NCP + lane];
            acc2 += g[(size_t)s1 * NCP + lane];
        }
    }
    if (j < end && lane < NCP) acc += g[(size_t)csr[j] * NCP + lane];
    if (lane < NC) out[(size_t)node * NC + lane] = (acc + acc2) * normD[node] + b2[lane];
}

// A[N][128] @ W[128][DOUT], 2 rows per thread (W-load reuse -> FMA-bound).
// EPI: out = relu?(acc*normD[row] + b[j]) * (NS ? normS[row] : 1), stride DOUT.
// !EPI: out = acc, stride DOUT_PAD (padding cols are 0 since Wl zero-padded).
template<int DOUT, int DOUT_PAD, bool EPI, bool ACT, bool NS>
__global__ __launch_bounds__(256) void gemm2_kernel(const float* __restrict__ A,
        const float* __restrict__ W, const float* __restrict__ b,
        const float* __restrict__ normD, const float* __restrict__ normS,
        float* __restrict__ out) {
    __shared__ float Wl[DF * DOUT_PAD];
    for (int i = threadIdx.x; i < DF * DOUT_PAD; i += 256) {
        int k = i / DOUT_PAD, j = i % DOUT_PAD;
        Wl[i] = (j < DOUT) ? W[k * DOUT + j] : 0.f;
    }
    __syncthreads();
    constexpr int TPR = DOUT_PAD / 4;  // threads per row-pair
    int gid = blockIdx.x * 256 + threadIdx.x;
    int p = gid / TPR;
    int jc = (gid % TPR) * 4;
    int r0 = p * 2;
    if (r0 >= NN) return;             // NN even -> r0+1 < NN too
    const float* a0 = A + (size_t)r0 * DF;
    const float* a1 = a0 + DF;
    float acc0[4] = {0.f, 0.f, 0.f, 0.f};
    float acc1[4] = {0.f, 0.f, 0.f, 0.f};
    for (int k0 = 0; k0 < DF; k0 += 4) {
        float4 x0 = *(const float4*)(a0 + k0);
        float4 x1 = *(const float4*)(a1 + k0);
        const float* xf0 = (const float*)&x0;
        const float* xf1 = (const float*)&x1;
        #pragma unroll
        for (int kk = 0; kk < 4; kk++) {
            float4 w = *(const float4*)(&Wl[(k0 + kk) * DOUT_PAD + jc]);
            float av0 = xf0[kk], av1 = xf1[kk];
            acc0[0] += av0 * w.x; acc0[1] += av0 * w.y;
            acc0[2] += av0 * w.z; acc0[3] += av0 * w.w;
            acc1[0] += av1 * w.x; acc1[1] += av1 * w.y;
            acc1[2] += av1 * w.z; acc1[3] += av1 * w.w;
        }
    }
    if (EPI) {
        float sd0 = normD[r0], sd1 = normD[r0 + 1];
        float ss0 = NS ? normS[r0] : 1.f, ss1 = NS ? normS[r0 + 1] : 1.f;
        #pragma unroll
        for (int i = 0; i < 4; i++) {
            int j = jc + i;
            if (j < DOUT) {
                float v0 = acc0[i] * sd0 + b[j];
                float v1 = acc1[i] * sd1 + b[j];
                if (ACT) { v0 = fmaxf(v0, 0.f); v1 = fmaxf(v1, 0.f); }
                out[(size_t)r0 * DOUT + j] = v0 * ss0;
                out[(size_t)(r0 + 1) * DOUT + j] = v1 * ss1;
            }
        }
    } else {
        *(float4*)(out + (size_t)r0 * DOUT_PAD + jc) =
            make_float4(acc0[0], acc0[1], acc0[2], acc0[3]);
        *(float4*)(out + (size_t)(r0 + 1) * DOUT_PAD + jc) =
            make_float4(acc1[0], acc1[1], acc1[2], acc1[3]);
    }
}

extern "C" void kernel_launch(void* const* d_in, const int* in_sizes, int n_in,
                              void* d_out, int out_size, void* d_ws, size_t ws_size,
                              hipStream_t stream) {
    const float* x   = (const float*)d_in[0];
    const int*   src = (const int*)d_in[1];
    const int*   dst = (const int*)d_in[2];
    const float* W0  = (const float*)d_in[3];
    const float* b0  = (const float*)d_in[4];
    const float* W1  = (const float*)d_in[5];
    const float* b1  = (const float*)d_in[6];
    const float* W2  = (const float*)d_in[7];
    const float* b2  = (const float*)d_in[8];
    float* out = (float*)d_out;

    float* ws     = (float*)d_ws;
    float* normS  = ws;                              // NPAD floats (int counts -> float)
    float* normD  = ws + NPAD;                       // NPAD floats
    int*   cntD   = (int*)(ws + 2 * (size_t)NPAD);   // NPAD ints (counts, then fill ctrs)
    int*   rowptr = cntD + NPAD;                     // NPAD ints (NN+1 used)
    int*   csr    = rowptr + NPAD;                   // NE ints
    int*   bsum   = csr + NE;                        // 128 ints
    float* bufA   = (float*)(bsum + 128);            // NN*DF floats
    float* bufB   = bufA + (size_t)NN * DF;          // NN*DF floats

    // ---- graph prep (ws is re-poisoned before every call) ----
    hipMemsetAsync(normS, 0, NPAD * sizeof(int), stream);
    hipMemsetAsync(cntD, 0, NPAD * sizeof(int), stream);
    deg_kernel<<<(NE + 255) / 256, 256, 0, stream>>>(src, dst, (int*)normS, cntD);
    scan1_kernel<<<SBLK, 1024, 0, stream>>>(cntD, rowptr, bsum);
    scan2_kernel<<<1, 128, 0, stream>>>(bsum);
    scan3_kernel<<<SBLK, 1024, 0, stream>>>(rowptr, bsum);
    norm_kernel<<<(NN + 255) / 256, 256, 0, stream>>>(normS, cntD, normD);
    hipMemsetAsync(cntD, 0, NPAD * sizeof(int), stream);  // reuse as fill counters
    fill_kernel<<<(NE + 255) / 256, 256, 0, stream>>>(src, dst, rowptr, cntD, csr);

    // ---- layer 0: B = gather(relu(x)*normS); A = relu((B@W0)*normD + b0)*normS
    gather128_kernel<true><<<(NN + 3) / 4, 256, 0, stream>>>(x, normS, rowptr, csr, bufB);
    gemm2_kernel<DF, DF, true, true, true><<<NN / 2 * (DF / 4) / 256, 256, 0, stream>>>(
        bufB, W0, b0, normD, normS, bufA);

    // ---- layer 1: B = gather(A); A = relu((B@W1)*normD + b1)*normS
    gather128_kernel<false><<<(NN + 3) / 4, 256, 0, stream>>>(bufA, nullptr, rowptr, csr, bufB);
    gemm2_kernel<DF, DF, true, true, true><<<NN / 2 * (DF / 4) / 256, 256, 0, stream>>>(
        bufB, W1, b1, normD, normS, bufA);

    // ---- layer 2 (GEMM-first): B = A @ W2 (48-wide); out = gather48(B)*normD + b2
    gemm2_kernel<NC, NCP, false, false, false>
        <<<(NN / 2 * (NCP / 4) + 255) / 256, 256, 0, stream>>>(
        bufA, W2, nullptr, nullptr, nullptr, bufB);
    gather48_kernel<<<(NN + 3) / 4, 256, 0, stream>>>(bufB, rowptr, csr, normD, b2, out);
}

// Round 7
// 809.816 us; speedup vs baseline: 8.5018x; 1.0698x over previous
//
#include <hip/hip_runtime.h>

#define NN 100000
#define NE 1600000
#define DF 128
#define NC 47
#define NCP 48

constexpr int NPAD = 100352;   // padded node count (= 98 * 1024)
constexpr int SBLK = 98;       // scan blocks

// Histogram src (cntS, punned into normS buffer) and dst (cntD); rank[e] = arrival
// index of edge e within its dst bucket (makes fill_kernel atomic-free).
__global__ __launch_bounds__(256) void deg_kernel(const int* __restrict__ src,
        const int* __restrict__ dst, int* __restrict__ cntS, int* __restrict__ cntD,
        int* __restrict__ rank) {
    int e = blockIdx.x * 256 + threadIdx.x;
    if (e < NE) {
        atomicAdd(&cntS[src[e]], 1);
        rank[e] = atomicAdd(&cntD[dst[e]], 1);
    }
}

// normS: in-place int count -> rsqrt float. normD: from cntD (cntD preserved).
__global__ __launch_bounds__(256) void norm_kernel(float* __restrict__ normS,
        const int* __restrict__ cntD, float* __restrict__ normD) {
    int i = blockIdx.x * 256 + threadIdx.x;
    if (i < NN) {
        int cs = ((const int*)normS)[i];
        normS[i] = rsqrtf(fmaxf((float)cs, 1.0f));
        normD[i] = rsqrtf(fmaxf((float)cntD[i], 1.0f));
    }
}

// ---- 3-pass exclusive scan of cnt[NPAD] -> rowptr ----
__global__ __launch_bounds__(1024) void scan1_kernel(const int* __restrict__ cnt,
        int* __restrict__ rowptr, int* __restrict__ bsum) {
    __shared__ int tmp[1024];
    int t = threadIdx.x;
    int g = blockIdx.x * 1024 + t;
    int v = cnt[g];          // tail (>= NN) zeroed by memset
    tmp[t] = v;
    __syncthreads();
    for (int off = 1; off < 1024; off <<= 1) {
        int u = (t >= off) ? tmp[t - off] : 0;
        __syncthreads();
        tmp[t] += u;
        __syncthreads();
    }
    rowptr[g] = tmp[t] - v;                    // exclusive within block
    if (t == 1023) bsum[blockIdx.x] = tmp[t];  // block total
}

__global__ __launch_bounds__(128) void scan2_kernel(int* __restrict__ bsum) {
    __shared__ int tmp[128];
    int t = threadIdx.x;
    int v = (t < SBLK) ? bsum[t] : 0;
    tmp[t] = v;
    __syncthreads();
    for (int off = 1; off < 128; off <<= 1) {
        int u = (t >= off) ? tmp[t - off] : 0;
        __syncthreads();
        tmp[t] += u;
        __syncthreads();
    }
    if (t < SBLK) bsum[t] = tmp[t] - v;        // exclusive block offsets, in place
}

__global__ __launch_bounds__(1024) void scan3_kernel(int* __restrict__ rowptr,
        const int* __restrict__ bsum) {
    int g = blockIdx.x * 1024 + threadIdx.x;
    rowptr[g] += bsum[blockIdx.x];
}

// Atomic-free counting-sort placement: csr[rowptr[d] + rank[e]] = src[e]
__global__ __launch_bounds__(256) void fill_kernel(const int* __restrict__ src,
        const int* __restrict__ dst, const int* __restrict__ rowptr,
        const int* __restrict__ rank, int* __restrict__ csr) {
    int e = blockIdx.x * 256 + threadIdx.x;
    if (e < NE) {
        int d = dst[e];
        csr[rowptr[d] + rank[e]] = src[e];
    }
}

// One wave per node: out[node][:] = sum over CSR neighbors of f(hs[s][:]). 128 wide.
// PRE: f = relu(.) * normS[s]  (layer-0, reads x directly). 4-deep MLP.
template<bool PRE>
__global__ __launch_bounds__(256) void gather128_kernel(const float* __restrict__ hs,
        const float* __restrict__ normS, const int* __restrict__ rowptr,
        const int* __restrict__ csr, float* __restrict__ out) {
    int node = __builtin_amdgcn_readfirstlane(blockIdx.x * 4 + (threadIdx.x >> 6));
    int lane = threadIdx.x & 63;
    if (node >= NN) return;
    int beg = rowptr[node], end = rowptr[node + 1];
    float2 a0 = {0.f, 0.f}, a1 = {0.f, 0.f}, a2 = {0.f, 0.f}, a3 = {0.f, 0.f};
    int j = beg;
    for (; j + 3 < end; j += 4) {
        int s0 = csr[j], s1 = csr[j + 1], s2 = csr[j + 2], s3 = csr[j + 3];
        float2 v0 = *(const float2*)(hs + (size_t)s0 * DF + lane * 2);
        float2 v1 = *(const float2*)(hs + (size_t)s1 * DF + lane * 2);
        float2 v2 = *(const float2*)(hs + (size_t)s2 * DF + lane * 2);
        float2 v3 = *(const float2*)(hs + (size_t)s3 * DF + lane * 2);
        if (PRE) {
            float w0 = normS[s0], w1 = normS[s1], w2 = normS[s2], w3 = normS[s3];
            v0.x = fmaxf(v0.x, 0.f) * w0; v0.y = fmaxf(v0.y, 0.f) * w0;
            v1.x = fmaxf(v1.x, 0.f) * w1; v1.y = fmaxf(v1.y, 0.f) * w1;
            v2.x = fmaxf(v2.x, 0.f) * w2; v2.y = fmaxf(v2.y, 0.f) * w2;
            v3.x = fmaxf(v3.x, 0.f) * w3; v3.y = fmaxf(v3.y, 0.f) * w3;
        }
        a0.x += v0.x; a0.y += v0.y;
        a1.x += v1.x; a1.y += v1.y;
        a2.x += v2.x; a2.y += v2.y;
        a3.x += v3.x; a3.y += v3.y;
    }
    for (; j < end; j++) {
        int s = csr[j];
        float2 v = *(const float2*)(hs + (size_t)s * DF + lane * 2);
        if (PRE) {
            float w = normS[s];
            v.x = fmaxf(v.x, 0.f) * w; v.y = fmaxf(v.y, 0.f) * w;
        }
        a0.x += v.x; a0.y += v.y;
    }
    a0.x += a1.x + a2.x + a3.x;
    a0.y += a1.y + a2.y + a3.y;
    *(float2*)(out + (size_t)node * DF + lane * 2) = a0;
}

// One wave per node, 48 wide, 4-deep MLP; fused epilogue: out = acc*normD[n] + b2[j]
__global__ __launch_bounds__(256) void gather48_kernel(const float* __restrict__ g,
        const int* __restrict__ rowptr, const int* __restrict__ csr,
        const float* __restrict__ normD, const float* __restrict__ b2,
        float* __restrict__ out) {
    int node = __builtin_amdgcn_readfirstlane(blockIdx.x * 4 + (threadIdx.x >> 6));
    int lane = threadIdx.x & 63;
    if (node >= NN) return;
    int beg = rowptr[node], end = rowptr[node + 1];
    float a0 = 0.f, a1 = 0.f, a2 = 0.f, a3 = 0.f;
    int j = beg;
    bool act = lane < NCP;
    for (; j + 3 < end; j += 4) {
        int s0 = csr[j], s1 = csr[j + 1], s2 = csr[j + 2], s3 = csr[j + 3];
        if (act) {
            a0 += g[(size_t)s0 * NCP + lane];
            a1 += g[(size_t)s1 * NCP + lane];
            a2 += g[(size_t)s2 * NCP + lane];
            a3 += g[(size_t)s3 * NCP + lane];
        }
    }
    for (; j < end; j++) {
        if (act) a0 += g[(size_t)csr[j] * NCP + lane];
    }
    if (lane < NC) out[(size_t)node * NC + lane] = (a0 + a1 + a2 + a3) * normD[node] + b2[lane];
}

// A[N][128] @ W[128][DOUT], 2 rows per thread (W-load reuse -> FMA-bound).
// EPI: out = relu?(acc*normD[row] + b[j]) * (NS ? normS[row] : 1), stride DOUT.
// !EPI: out = acc, stride DOUT_PAD (padding cols are 0 since Wl zero-padded).
template<int DOUT, int DOUT_PAD, bool EPI, bool ACT, bool NS>
__global__ __launch_bounds__(256) void gemm2_kernel(const float* __restrict__ A,
        const float* __restrict__ W, const float* __restrict__ b,
        const float* __restrict__ normD, const float* __restrict__ normS,
        float* __restrict__ out) {
    __shared__ float Wl[DF * DOUT_PAD];
    for (int i = threadIdx.x; i < DF * DOUT_PAD; i += 256) {
        int k = i / DOUT_PAD, j = i % DOUT_PAD;
        Wl[i] = (j < DOUT) ? W[k * DOUT + j] : 0.f;
    }
    __syncthreads();
    constexpr int TPR = DOUT_PAD / 4;  // threads per row-pair
    int gid = blockIdx.x * 256 + threadIdx.x;
    int p = gid / TPR;
    int jc = (gid % TPR) * 4;
    int r0 = p * 2;
    if (r0 >= NN) return;             // NN even -> r0+1 < NN too
    const float* a0 = A + (size_t)r0 * DF;
    const float* a1 = a0 + DF;
    float acc0[4] = {0.f, 0.f, 0.f, 0.f};
    float acc1[4] = {0.f, 0.f, 0.f, 0.f};
    for (int k0 = 0; k0 < DF; k0 += 4) {
        float4 x0 = *(const float4*)(a0 + k0);
        float4 x1 = *(const float4*)(a1 + k0);
        const float* xf0 = (const float*)&x0;
        const float* xf1 = (const float*)&x1;
        #pragma unroll
        for (int kk = 0; kk < 4; kk++) {
            float4 w = *(const float4*)(&Wl[(k0 + kk) * DOUT_PAD + jc]);
            float av0 = xf0[kk], av1 = xf1[kk];
            acc0[0] += av0 * w.x; acc0[1] += av0 * w.y;
            acc0[2] += av0 * w.z; acc0[3] += av0 * w.w;
            acc1[0] += av1 * w.x; acc1[1] += av1 * w.y;
            acc1[2] += av1 * w.z; acc1[3] += av1 * w.w;
        }
    }
    if (EPI) {
        float sd0 = normD[r0], sd1 = normD[r0 + 1];
        float ss0 = NS ? normS[r0] : 1.f, ss1 = NS ? normS[r0 + 1] : 1.f;
        #pragma unroll
        for (int i = 0; i < 4; i++) {
            int j = jc + i;
            if (j < DOUT) {
                float v0 = acc0[i] * sd0 + b[j];
                float v1 = acc1[i] * sd1 + b[j];
                if (ACT) { v0 = fmaxf(v0, 0.f); v1 = fmaxf(v1, 0.f); }
                out[(size_t)r0 * DOUT + j] = v0 * ss0;
                out[(size_t)(r0 + 1) * DOUT + j] = v1 * ss1;
            }
        }
    } else {
        *(float4*)(out + (size_t)r0 * DOUT_PAD + jc) =
            make_float4(acc0[0], acc0[1], acc0[2], acc0[3]);
        *(float4*)(out + (size_t)(r0 + 1) * DOUT_PAD + jc) =
            make_float4(acc1[0], acc1[1], acc1[2], acc1[3]);
    }
}

extern "C" void kernel_launch(void* const* d_in, const int* in_sizes, int n_in,
                              void* d_out, int out_size, void* d_ws, size_t ws_size,
                              hipStream_t stream) {
    const float* x   = (const float*)d_in[0];
    const int*   src = (const int*)d_in[1];
    const int*   dst = (const int*)d_in[2];
    const float* W0  = (const float*)d_in[3];
    const float* b0  = (const float*)d_in[4];
    const float* W1  = (const float*)d_in[5];
    const float* b1  = (const float*)d_in[6];
    const float* W2  = (const float*)d_in[7];
    const float* b2  = (const float*)d_in[8];
    float* out = (float*)d_out;

    // ws layout: cntS|cntD adjacent -> single memset. normD needs no zeroing.
    float* ws     = (float*)d_ws;
    float* normS  = ws;                              // NPAD (int counts -> float in place)
    int*   cntD   = (int*)(ws + NPAD);               // NPAD ints (kept for norm_kernel)
    float* normD  = ws + 2 * (size_t)NPAD;           // NPAD floats
    int*   rowptr = (int*)(ws + 3 * (size_t)NPAD);   // NPAD ints (NN+1 used)
    int*   csr    = rowptr + NPAD;                   // NE ints
    int*   bsum   = csr + NE;                        // 128 ints
    float* bufA   = (float*)(bsum + 128);            // NN*DF floats
    float* bufB   = bufA + (size_t)NN * DF;          // NN*DF floats
    int*   rank   = (int*)bufB;                      // NE ints, aliases bufB (free until gather)

    // ---- graph prep ----
    hipMemsetAsync(normS, 0, 2 * (size_t)NPAD * sizeof(int), stream);  // cntS + cntD
    deg_kernel<<<(NE + 255) / 256, 256, 0, stream>>>(src, dst, (int*)normS, cntD, rank);
    scan1_kernel<<<SBLK, 1024, 0, stream>>>(cntD, rowptr, bsum);
    scan2_kernel<<<1, 128, 0, stream>>>(bsum);
    scan3_kernel<<<SBLK, 1024, 0, stream>>>(rowptr, bsum);
    norm_kernel<<<(NN + 255) / 256, 256, 0, stream>>>(normS, cntD, normD);
    fill_kernel<<<(NE + 255) / 256, 256, 0, stream>>>(src, dst, rowptr, rank, csr);

    // ---- layer 0: B = gather(relu(x)*normS); A = relu((B@W0)*normD + b0)*normS
    gather128_kernel<true><<<(NN + 3) / 4, 256, 0, stream>>>(x, normS, rowptr, csr, bufB);
    gemm2_kernel<DF, DF, true, true, true><<<NN / 2 * (DF / 4) / 256, 256, 0, stream>>>(
        bufB, W0, b0, normD, normS, bufA);

    // ---- layer 1: B = gather(A); A = relu((B@W1)*normD + b1)*normS
    gather128_kernel<false><<<(NN + 3) / 4, 256, 0, stream>>>(bufA, nullptr, rowptr, csr, bufB);
    gemm2_kernel<DF, DF, true, true, true><<<NN / 2 * (DF / 4) / 256, 256, 0, stream>>>(
        bufB, W1, b1, normD, normS, bufA);

    // ---- layer 2 (GEMM-first): B = A @ W2 (48-wide); out = gather48(B)*normD + b2
    gemm2_kernel<NC, NCP, false, false, false>
        <<<(NN / 2 * (NCP / 4) + 255) / 256, 256, 0, stream>>>(
        bufA, W2, nullptr, nullptr, nullptr, bufB);
    gather48_kernel<<<(NN + 3) / 4, 256, 0, stream>>>(bufB, rowptr, csr, normD, b2, out);
}